// Round 1
// baseline (363.896 us; speedup 1.0000x reference)
//
#include <hip/hip_runtime.h>
#include <hip/hip_bf16.h>
#include <hip/hip_fp16.h>
#include <math.h>

#define N_NODES 100000
#define N_EDGES 1600000
#define F_IN 16
#define HDIM 64
#define E_DIM 9
#define NEG 0.2f

#define CAP 64                            // bucket capacity/node (Poisson(16), 12-sigma)
#define NSLICE 8
#define SLICE_W 12500                     // dst-slice width (100000/8)
#define SLICE_CAP 210000                  // per-slice stream capacity
#define PART_BLOCKS 1024                  // 8 slices x 128 blocks
#define FIXSCALE 16777216.0f              // 2^24 fixed-point for sum_ae
#define GPAD 64                           // gcount padding: 1 counter per 256 B line

typedef unsigned long long ull;
typedef long long ll;

__device__ __forceinline__ void bf2(unsigned u, float& lo, float& hi) {
  lo = __uint_as_float(u << 16);
  hi = __uint_as_float(u & 0xFFFF0000u);
}

// ---- K1: a_src/a_dst = (x@W)@att (wave per node); store x as bf16 row (32 B) ----
__global__ __launch_bounds__(256) void k_node_h(
    const float* __restrict__ x, const float* __restrict__ W,
    const float* __restrict__ att_src, const float* __restrict__ att_dst,
    __hip_bfloat16* __restrict__ xbf, float* __restrict__ a_src,
    float* __restrict__ a_dst) {
  __shared__ float sW[F_IN * HDIM];
  int t = threadIdx.x;
  for (int i = t; i < F_IN * HDIM; i += 256) sW[i] = W[i];
  __syncthreads();
  int lane = t & 63;
  int node = blockIdx.x * 4 + (t >> 6);
  if (node >= N_NODES) return;
  const float* xr = x + node * F_IN;
  float acc = 0.f;
#pragma unroll
  for (int k = 0; k < F_IN; ++k) acc += xr[k] * sW[k * HDIM + lane];
  if (lane < F_IN) xbf[(size_t)node * F_IN + lane] = __float2bfloat16(xr[lane]);
  float v1 = acc * att_src[lane];
  float v2 = acc * att_dst[lane];
#pragma unroll
  for (int off = 32; off > 0; off >>= 1) {
    v1 += __shfl_down(v1, off);
    v2 += __shfl_down(v2, off);
  }
  if (lane == 0) { a_src[node] = v1; a_dst[node] = v2; }
}

// ---- tiny: w_e[d] = sum_h W_edge[d,h]*att_edge[h] ----
__global__ void k_we(const float* __restrict__ W_edge,
                     const float* __restrict__ att_edge, float* __restrict__ w_e) {
  int d = threadIdx.x;
  if (d < E_DIM) {
    float s = 0.f;
    for (int hh = 0; hh < HDIM; ++hh) s += W_edge[d * HDIM + hh] * att_edge[hh];
    w_e[d] = s;
  }
}

// ---- K2: a_e dot + 8-way dst-slice partition (ballot compaction). NO random
// gathers, no exp — pure stream. Entry = {dloc:16 | fp16(a_e):16 | src:32}.
// gcount padded (R11: same-line atomics serialize ~2.5ns each). ----
__global__ __launch_bounds__(256) void k_edge_pre(
    const float* __restrict__ ea, const int* __restrict__ ei,
    const float* __restrict__ w_e, ull* __restrict__ sstream,
    unsigned* __restrict__ gcount) {
  __shared__ float sea[256 * E_DIM];
  __shared__ float swe[E_DIM];
  __shared__ unsigned wcnt[4][NSLICE];
  __shared__ unsigned woff[4][NSLICE];
  __shared__ unsigned gbase[NSLICE];
  int t = threadIdx.x;
  int wave = t >> 6, lane = t & 63;
  if (t < E_DIM) swe[t] = w_e[t];
  size_t tile = (size_t)blockIdx.x * (256 * E_DIM);
#pragma unroll
  for (int i = 0; i < E_DIM; ++i)
    sea[i * 256 + t] = __builtin_nontemporal_load(ea + tile + i * 256 + t);
  int e = blockIdx.x * 256 + t;
  int s = __builtin_nontemporal_load(ei + e);
  int d = __builtin_nontemporal_load(ei + N_EDGES + e);
  __syncthreads();
  float a_e = 0.f;
#pragma unroll
  for (int k = 0; k < E_DIM; ++k) a_e += sea[t * E_DIM + k] * swe[k];
  unsigned slice = (unsigned)d / SLICE_W;
  unsigned dloc = (unsigned)d - slice * SLICE_W;
  unsigned aeh = (unsigned)__half_as_ushort(__float2half(a_e));
  ull entry = ((ull)dloc << 48) | ((ull)aeh << 32) | (ull)(unsigned)s;
  // wave-level ranking via ballot
  ull lt = (lane == 63) ? 0x7FFFFFFFFFFFFFFFull : ((1ull << lane) - 1ull);
  unsigned myrank = 0;
#pragma unroll
  for (int si = 0; si < NSLICE; ++si) {
    ull m = __ballot(slice == (unsigned)si);
    if (slice == (unsigned)si) myrank = (unsigned)__popcll(m & lt);
    if (lane == 0) wcnt[wave][si] = (unsigned)__popcll(m);
  }
  __syncthreads();
  if (t < NSLICE) {
    unsigned a = 0;
#pragma unroll
    for (int w = 0; w < 4; ++w) { woff[w][t] = a; a += wcnt[w][t]; }
    gbase[t] = atomicAdd(gcount + t * GPAD, a);
  }
  __syncthreads();
  unsigned off = gbase[slice] + woff[wave][slice] + myrank;
  if (off < SLICE_CAP)
    __builtin_nontemporal_store(entry, sstream + (size_t)slice * SLICE_CAP + off);
}

// ---- K3: distribute within slice + FULL logit math (moved here: the a_src
// gather and exp hide under the atomic latency; a_dst is slice-local 50 KB).
// One fused 64-bit atomic per edge: count++ (low 20b, old = bucket pos) +
// sum_ae in 2^-24 fixpt (high 44b). blockIdx%8 -> XCD-resident bucket slice. ----
__global__ __launch_bounds__(256) void k_part2(
    const ull* __restrict__ sstream, const unsigned* __restrict__ gcount,
    const float* __restrict__ a_src, const float* __restrict__ a_dst,
    ull* __restrict__ packed, unsigned* __restrict__ bpack) {
  int t = threadIdx.x;
  int slice = blockIdx.x & (NSLICE - 1);
  int j = blockIdx.x >> 3;
  unsigned n = gcount[slice * GPAD];
  const ull* sp = sstream + (size_t)slice * SLICE_CAP;
  int lo = slice * SLICE_W;
  const unsigned stride = (PART_BLOCKS / NSLICE) * 256;
  for (unsigned i = (unsigned)j * 256 + t; i < n; i += stride) {
    ull entry = sp[i];
    unsigned src = (unsigned)(entry & 0xFFFFFFFFu);
    float ae = __half2float(__ushort_as_half((unsigned short)((entry >> 32) & 0xFFFFu)));
    int d = lo + (int)(unsigned)(entry >> 48);
    float al = a_src[src] + a_dst[d] + ae;
    al = al >= 0.f ? al : NEG * al;
    float ee = expf(al);  // shift-invariant softmax: max-subtract skipped
    unsigned b = __float_as_uint(ee);
    b += 0x7fffu + ((b >> 16) & 1u);
    unsigned pk = (src << 15) | ((b >> 16) & 0x7fffu);
    ll q = (ll)lrintf(ae * FIXSCALE);
    ull old = atomicAdd(packed + d, ((ull)q << 20) | 1ull);
    unsigned pos = (unsigned)(old & 0xFFFFFu);
    if (pos < CAP) bpack[(size_t)d * CAP + pos] = pk;
  }
}

// ---- K4: gather in x-space (rank-16): Sum ee*h[src] == (Sum ee*x[src])@W.
// 16 threads/node accumulate acc[16] from bf16 x rows (32 B/edge, 3.2 MB
// table -> L2-resident), shuffle-reduce, then 16x64 GEMV from LDS W with
// fused relu/bias/lin_w epilogue. ----
__global__ __launch_bounds__(256) void k_gather(
    const ull* __restrict__ packed, const unsigned* __restrict__ bpack,
    const __hip_bfloat16* __restrict__ xbf, const float* __restrict__ W,
    const float* __restrict__ a_src, const float* __restrict__ a_dst,
    const float* __restrict__ bias, const float* __restrict__ lin_w,
    float* __restrict__ s_node) {
  __shared__ float sW[F_IN * HDIM];
  int t = threadIdx.x;
  for (int i = t; i < F_IN * HDIM; i += 256) sW[i] = W[i];
  __syncthreads();
  int g = t >> 4, i = t & 15;
  int node = blockIdx.x * 16 + g;
  if (node >= N_NODES) return;
  ull p = packed[node];
  unsigned deg = (unsigned)(p & 0xFFFFFu);
  float sumae = (float)((double)((ll)p >> 20) * (1.0 / (double)FIXSCALE));
  unsigned degc = deg < CAP ? deg : CAP;
  const unsigned* row = bpack + (size_t)node * CAP;
  float acc[F_IN];
#pragma unroll
  for (int j = 0; j < F_IN; ++j) acc[j] = 0.f;
  float denom = 0.f;
  for (unsigned k = i; k < degc; k += 16) {
    unsigned pe = row[k];
    float ee = __uint_as_float((pe & 0x7fffu) << 16);
    unsigned src = pe >> 15;
    const uint4* xp = (const uint4*)(xbf + (size_t)src * F_IN);
    uint4 xa = xp[0], xb = xp[1];
    denom += ee;
    float f0, f1;
    bf2(xa.x, f0, f1); acc[0] += ee * f0; acc[1] += ee * f1;
    bf2(xa.y, f0, f1); acc[2] += ee * f0; acc[3] += ee * f1;
    bf2(xa.z, f0, f1); acc[4] += ee * f0; acc[5] += ee * f1;
    bf2(xa.w, f0, f1); acc[6] += ee * f0; acc[7] += ee * f1;
    bf2(xb.x, f0, f1); acc[8] += ee * f0; acc[9] += ee * f1;
    bf2(xb.y, f0, f1); acc[10] += ee * f0; acc[11] += ee * f1;
    bf2(xb.z, f0, f1); acc[12] += ee * f0; acc[13] += ee * f1;
    bf2(xb.w, f0, f1); acc[14] += ee * f0; acc[15] += ee * f1;
  }
  // reduce denom + acc[16] across the 16 lanes of this node-group
#pragma unroll
  for (int off = 8; off > 0; off >>= 1) {
    denom += __shfl_xor(denom, off, 16);
#pragma unroll
    for (int j = 0; j < F_IN; ++j) acc[j] += __shfl_xor(acc[j], off, 16);
  }
  // self-loop (fill_value='mean'): logit uses mean of incident a_e
  float cnt = (float)deg;
  float all = a_src[node] + a_dst[node] + sumae / fmaxf(cnt, 1.f);
  all = all >= 0.f ? all : NEG * all;
  float eel = expf(all);
  denom += eel;
  {
    const uint4* xp = (const uint4*)(xbf + (size_t)node * F_IN);
    uint4 xa = xp[0], xb = xp[1];
    float f0, f1;
    bf2(xa.x, f0, f1); acc[0] += eel * f0; acc[1] += eel * f1;
    bf2(xa.y, f0, f1); acc[2] += eel * f0; acc[3] += eel * f1;
    bf2(xa.z, f0, f1); acc[4] += eel * f0; acc[5] += eel * f1;
    bf2(xa.w, f0, f1); acc[6] += eel * f0; acc[7] += eel * f1;
    bf2(xb.x, f0, f1); acc[8] += eel * f0; acc[9] += eel * f1;
    bf2(xb.y, f0, f1); acc[10] += eel * f0; acc[11] += eel * f1;
    bf2(xb.z, f0, f1); acc[12] += eel * f0; acc[13] += eel * f1;
    bf2(xb.w, f0, f1); acc[14] += eel * f0; acc[15] += eel * f1;
  }
  float inv = 1.f / (denom + 1e-16f);
  // 16x64 GEMV + relu/bias/lin_w epilogue: lane i handles h = i+16*step
  float o = 0.f;
#pragma unroll
  for (int stp = 0; stp < 4; ++stp) {
    int h = i + stp * 16;
    float oh = 0.f;
#pragma unroll
    for (int j = 0; j < F_IN; ++j) oh += acc[j] * sW[j * HDIM + h];
    o += fmaxf(oh * inv + bias[h], 0.f) * lin_w[h];
  }
#pragma unroll
  for (int off = 8; off > 0; off >>= 1) o += __shfl_xor(o, off, 16);
  if (i == 0) s_node[node] = o;
}

// ---- K5: out[e] = sigmoid(0.5*(s[src]+s[dst]) + lin_b) ----
__global__ __launch_bounds__(256) void k_out(
    const int* __restrict__ ei, const float* __restrict__ s_node,
    const float* __restrict__ lin_b, float* __restrict__ out) {
  int e = blockIdx.x * 256 + threadIdx.x;
  if (e >= N_EDGES) return;
  int s = __builtin_nontemporal_load(ei + e);
  int d = __builtin_nontemporal_load(ei + N_EDGES + e);
  float z = 0.5f * (s_node[s] + s_node[d]) + lin_b[0];
  float r = 1.f / (1.f + expf(-z));
  __builtin_nontemporal_store(r, out + e);
}

extern "C" void kernel_launch(void* const* d_in, const int* in_sizes, int n_in,
                              void* d_out, int out_size, void* d_ws, size_t ws_size,
                              hipStream_t stream) {
  const float* x        = (const float*)d_in[0];
  const float* edge_attr= (const float*)d_in[1];
  const float* W        = (const float*)d_in[2];
  const float* W_edge   = (const float*)d_in[3];
  const float* att_src  = (const float*)d_in[4];
  const float* att_dst  = (const float*)d_in[5];
  const float* att_edge = (const float*)d_in[6];
  const float* bias     = (const float*)d_in[7];
  const float* lin_w    = (const float*)d_in[8];
  const float* lin_b    = (const float*)d_in[9];
  const int*   ei       = (const int*)d_in[10];
  float* out = (float*)d_out;

  // workspace layout (16-B alignment for xbf/sstream preserved)
  char* base = (char*)d_ws;
  __hip_bfloat16* xbf = (__hip_bfloat16*)base;                      // N*16*2 = 3.2 MB
  ull* sstream = (ull*)(base + (size_t)N_NODES * F_IN * 2);         // 8*210000*8 = 13.44 MB
  unsigned* bpack = (unsigned*)(sstream + (size_t)NSLICE * SLICE_CAP); // N*CAP*4 = 25.6 MB
  ull* packed = (ull*)(bpack + (size_t)N_NODES * CAP);              // N*8 = 0.8 MB (zeroed)
  unsigned* gcount = (unsigned*)(packed + N_NODES);                 // 8*64 u32 (zeroed)
  float* a_src  = (float*)(gcount + NSLICE * GPAD);                 // N
  float* a_dst  = a_src + N_NODES;                                  // N
  float* s_node = a_dst + N_NODES;                                  // N
  float* w_e    = s_node + N_NODES;                                 // 16
  // total ~ 44.3 MB

  hipMemsetAsync(packed, 0,
                 sizeof(ull) * N_NODES + sizeof(unsigned) * NSLICE * GPAD, stream);

  int nb_node   = (N_NODES + 3) / 4;
  int nb_edge_t = N_EDGES / 256;    // 6250, exact
  int nb_gather = (N_NODES + 15) / 16;

  k_node_h  <<<nb_node, 256, 0, stream>>>(x, W, att_src, att_dst, xbf, a_src, a_dst);
  k_we      <<<1, 64, 0, stream>>>(W_edge, att_edge, w_e);
  k_edge_pre<<<nb_edge_t, 256, 0, stream>>>(edge_attr, ei, w_e, sstream, gcount);
  k_part2   <<<PART_BLOCKS, 256, 0, stream>>>(sstream, gcount, a_src, a_dst,
                                              packed, bpack);
  k_gather  <<<nb_gather, 256, 0, stream>>>(packed, bpack, xbf, W, a_src, a_dst,
                                            bias, lin_w, s_node);
  k_out     <<<nb_edge_t, 256, 0, stream>>>(ei, s_node, lin_b, out);
}

// Round 2
// 358.758 us; speedup vs baseline: 1.0143x; 1.0143x over previous
//
#include <hip/hip_runtime.h>
#include <hip/hip_bf16.h>
#include <hip/hip_fp16.h>
#include <math.h>

#define N_NODES 100000
#define N_EDGES 1600000
#define F_IN 16
#define HDIM 64
#define E_DIM 9
#define NEG 0.2f

#define CAP 64                            // bucket capacity/node (Poisson(16), 12-sigma)
#define NSLICE 8
#define SLICE_W 12500                     // dst-slice width (100000/8)
#define SLICE_CAP 210000                  // per-slice stream capacity
#define PART_BLOCKS 2048                  // 8 slices x 256 blocks (R1: was 1024; occupancy 39%->~78%)
#define PART_UNROLL 4                     // R1: 4 atomics in flight/thread (MLP)
#define FIXSCALE 16777216.0f              // 2^24 fixed-point for sum_ae
#define GPAD 64                           // gcount padding: 1 counter per 256 B line

typedef unsigned long long ull;
typedef long long ll;

__device__ __forceinline__ void bf2(unsigned u, float& lo, float& hi) {
  lo = __uint_as_float(u << 16);
  hi = __uint_as_float(u & 0xFFFF0000u);
}

// ---- K1: a_src/a_dst = (x@W)@att (wave per node); store x as bf16 row (32 B) ----
__global__ __launch_bounds__(256) void k_node_h(
    const float* __restrict__ x, const float* __restrict__ W,
    const float* __restrict__ att_src, const float* __restrict__ att_dst,
    __hip_bfloat16* __restrict__ xbf, float* __restrict__ a_src,
    float* __restrict__ a_dst) {
  __shared__ float sW[F_IN * HDIM];
  int t = threadIdx.x;
  for (int i = t; i < F_IN * HDIM; i += 256) sW[i] = W[i];
  __syncthreads();
  int lane = t & 63;
  int node = blockIdx.x * 4 + (t >> 6);
  if (node >= N_NODES) return;
  const float* xr = x + node * F_IN;
  float acc = 0.f;
#pragma unroll
  for (int k = 0; k < F_IN; ++k) acc += xr[k] * sW[k * HDIM + lane];
  if (lane < F_IN) xbf[(size_t)node * F_IN + lane] = __float2bfloat16(xr[lane]);
  float v1 = acc * att_src[lane];
  float v2 = acc * att_dst[lane];
#pragma unroll
  for (int off = 32; off > 0; off >>= 1) {
    v1 += __shfl_down(v1, off);
    v2 += __shfl_down(v2, off);
  }
  if (lane == 0) { a_src[node] = v1; a_dst[node] = v2; }
}

// ---- tiny: w_e[d] = sum_h W_edge[d,h]*att_edge[h] ----
__global__ void k_we(const float* __restrict__ W_edge,
                     const float* __restrict__ att_edge, float* __restrict__ w_e) {
  int d = threadIdx.x;
  if (d < E_DIM) {
    float s = 0.f;
    for (int hh = 0; hh < HDIM; ++hh) s += W_edge[d * HDIM + hh] * att_edge[hh];
    w_e[d] = s;
  }
}

// ---- K2: a_e dot + 8-way dst-slice partition (ballot compaction). NO random
// gathers, no exp — pure stream. Entry = {dloc:16 | fp16(a_e):16 | src:32}.
// gcount padded (R11: same-line atomics serialize ~2.5ns each). ----
__global__ __launch_bounds__(256) void k_edge_pre(
    const float* __restrict__ ea, const int* __restrict__ ei,
    const float* __restrict__ w_e, ull* __restrict__ sstream,
    unsigned* __restrict__ gcount) {
  __shared__ float sea[256 * E_DIM];
  __shared__ float swe[E_DIM];
  __shared__ unsigned wcnt[4][NSLICE];
  __shared__ unsigned woff[4][NSLICE];
  __shared__ unsigned gbase[NSLICE];
  int t = threadIdx.x;
  int wave = t >> 6, lane = t & 63;
  if (t < E_DIM) swe[t] = w_e[t];
  size_t tile = (size_t)blockIdx.x * (256 * E_DIM);
#pragma unroll
  for (int i = 0; i < E_DIM; ++i)
    sea[i * 256 + t] = __builtin_nontemporal_load(ea + tile + i * 256 + t);
  int e = blockIdx.x * 256 + t;
  int s = __builtin_nontemporal_load(ei + e);
  int d = __builtin_nontemporal_load(ei + N_EDGES + e);
  __syncthreads();
  float a_e = 0.f;
#pragma unroll
  for (int k = 0; k < E_DIM; ++k) a_e += sea[t * E_DIM + k] * swe[k];
  unsigned slice = (unsigned)d / SLICE_W;
  unsigned dloc = (unsigned)d - slice * SLICE_W;
  unsigned aeh = (unsigned)__half_as_ushort(__float2half(a_e));
  ull entry = ((ull)dloc << 48) | ((ull)aeh << 32) | (ull)(unsigned)s;
  // wave-level ranking via ballot
  ull lt = (lane == 63) ? 0x7FFFFFFFFFFFFFFFull : ((1ull << lane) - 1ull);
  unsigned myrank = 0;
#pragma unroll
  for (int si = 0; si < NSLICE; ++si) {
    ull m = __ballot(slice == (unsigned)si);
    if (slice == (unsigned)si) myrank = (unsigned)__popcll(m & lt);
    if (lane == 0) wcnt[wave][si] = (unsigned)__popcll(m);
  }
  __syncthreads();
  if (t < NSLICE) {
    unsigned a = 0;
#pragma unroll
    for (int w = 0; w < 4; ++w) { woff[w][t] = a; a += wcnt[w][t]; }
    gbase[t] = atomicAdd(gcount + t * GPAD, a);
  }
  __syncthreads();
  unsigned off = gbase[slice] + woff[wave][slice] + myrank;
  if (off < SLICE_CAP)
    __builtin_nontemporal_store(entry, sstream + (size_t)slice * SLICE_CAP + off);
}

// ---- K3: distribute within slice + FULL logit math. R1: latency-bound fix —
// hard-unroll x4 (n <= 210000 < 4*65536 covers the slice), batch entry loads,
// then gathers, then issue all 4 independent atomics BEFORE any dependent
// store (MLP 1->4). One fused 64-bit atomic per edge: count++ (low 20b, old =
// bucket pos) + sum_ae in 2^-24 fixpt (high 44b). blockIdx%8 -> XCD-resident
// bucket slice. ----
__global__ __launch_bounds__(256) void k_part2(
    const ull* __restrict__ sstream, const unsigned* __restrict__ gcount,
    const float* __restrict__ a_src, const float* __restrict__ a_dst,
    ull* __restrict__ packed, unsigned* __restrict__ bpack) {
  int t = threadIdx.x;
  int slice = blockIdx.x & (NSLICE - 1);
  int j = blockIdx.x >> 3;
  unsigned n = gcount[slice * GPAD];
  const ull* sp = sstream + (size_t)slice * SLICE_CAP;
  int lo = slice * SLICE_W;
  const unsigned stride = (PART_BLOCKS / NSLICE) * 256;   // 65536
  unsigned i0 = (unsigned)j * 256 + (unsigned)t;

  ull ent[PART_UNROLL];
  bool val[PART_UNROLL];
#pragma unroll
  for (int u = 0; u < PART_UNROLL; ++u) {
    unsigned i = i0 + (unsigned)u * stride;
    val[u] = (i < n);
    ent[u] = val[u] ? __builtin_nontemporal_load(sp + i) : 0ull;
  }
  float asv[PART_UNROLL], adv[PART_UNROLL];
#pragma unroll
  for (int u = 0; u < PART_UNROLL; ++u) {
    unsigned src = (unsigned)(ent[u] & 0xFFFFFFFFu);
    int d = lo + (int)(unsigned)(ent[u] >> 48);
    asv[u] = val[u] ? a_src[src] : 0.f;
    adv[u] = val[u] ? a_dst[d] : 0.f;
  }
  ull oldv[PART_UNROLL];
  unsigned pk[PART_UNROLL];
  int dd[PART_UNROLL];
#pragma unroll
  for (int u = 0; u < PART_UNROLL; ++u) {
    unsigned src = (unsigned)(ent[u] & 0xFFFFFFFFu);
    float ae = __half2float(__ushort_as_half((unsigned short)((ent[u] >> 32) & 0xFFFFu)));
    dd[u] = lo + (int)(unsigned)(ent[u] >> 48);
    float al = asv[u] + adv[u] + ae;
    al = al >= 0.f ? al : NEG * al;
    float ee = expf(al);  // shift-invariant softmax: max-subtract skipped
    unsigned b = __float_as_uint(ee);
    b += 0x7fffu + ((b >> 16) & 1u);
    pk[u] = (src << 15) | ((b >> 16) & 0x7fffu);
    ll q = (ll)lrintf(ae * FIXSCALE);
    if (val[u]) oldv[u] = atomicAdd(packed + dd[u], ((ull)q << 20) | 1ull);
  }
#pragma unroll
  for (int u = 0; u < PART_UNROLL; ++u) {
    if (val[u]) {
      unsigned pos = (unsigned)(oldv[u] & 0xFFFFFu);
      if (pos < CAP) bpack[(size_t)dd[u] * CAP + pos] = pk[u];
    }
  }
}

// ---- K4: gather in x-space (rank-16): Sum ee*h[src] == (Sum ee*x[src])@W.
// 16 threads/node accumulate acc[16] from bf16 x rows (32 B/edge, 3.2 MB
// table -> L2-resident), shuffle-reduce, then 16x64 GEMV from LDS W with
// fused relu/bias/lin_w epilogue. ----
__global__ __launch_bounds__(256) void k_gather(
    const ull* __restrict__ packed, const unsigned* __restrict__ bpack,
    const __hip_bfloat16* __restrict__ xbf, const float* __restrict__ W,
    const float* __restrict__ a_src, const float* __restrict__ a_dst,
    const float* __restrict__ bias, const float* __restrict__ lin_w,
    float* __restrict__ s_node) {
  __shared__ float sW[F_IN * HDIM];
  int t = threadIdx.x;
  for (int i = t; i < F_IN * HDIM; i += 256) sW[i] = W[i];
  __syncthreads();
  int g = t >> 4, i = t & 15;
  int node = blockIdx.x * 16 + g;
  if (node >= N_NODES) return;
  ull p = packed[node];
  unsigned deg = (unsigned)(p & 0xFFFFFu);
  float sumae = (float)((double)((ll)p >> 20) * (1.0 / (double)FIXSCALE));
  unsigned degc = deg < CAP ? deg : CAP;
  const unsigned* row = bpack + (size_t)node * CAP;
  float acc[F_IN];
#pragma unroll
  for (int j = 0; j < F_IN; ++j) acc[j] = 0.f;
  float denom = 0.f;
  for (unsigned k = i; k < degc; k += 16) {
    unsigned pe = row[k];
    float ee = __uint_as_float((pe & 0x7fffu) << 16);
    unsigned src = pe >> 15;
    const uint4* xp = (const uint4*)(xbf + (size_t)src * F_IN);
    uint4 xa = xp[0], xb = xp[1];
    denom += ee;
    float f0, f1;
    bf2(xa.x, f0, f1); acc[0] += ee * f0; acc[1] += ee * f1;
    bf2(xa.y, f0, f1); acc[2] += ee * f0; acc[3] += ee * f1;
    bf2(xa.z, f0, f1); acc[4] += ee * f0; acc[5] += ee * f1;
    bf2(xa.w, f0, f1); acc[6] += ee * f0; acc[7] += ee * f1;
    bf2(xb.x, f0, f1); acc[8] += ee * f0; acc[9] += ee * f1;
    bf2(xb.y, f0, f1); acc[10] += ee * f0; acc[11] += ee * f1;
    bf2(xb.z, f0, f1); acc[12] += ee * f0; acc[13] += ee * f1;
    bf2(xb.w, f0, f1); acc[14] += ee * f0; acc[15] += ee * f1;
  }
  // reduce denom + acc[16] across the 16 lanes of this node-group
#pragma unroll
  for (int off = 8; off > 0; off >>= 1) {
    denom += __shfl_xor(denom, off, 16);
#pragma unroll
    for (int j = 0; j < F_IN; ++j) acc[j] += __shfl_xor(acc[j], off, 16);
  }
  // self-loop (fill_value='mean'): logit uses mean of incident a_e
  float cnt = (float)deg;
  float all = a_src[node] + a_dst[node] + sumae / fmaxf(cnt, 1.f);
  all = all >= 0.f ? all : NEG * all;
  float eel = expf(all);
  denom += eel;
  {
    const uint4* xp = (const uint4*)(xbf + (size_t)node * F_IN);
    uint4 xa = xp[0], xb = xp[1];
    float f0, f1;
    bf2(xa.x, f0, f1); acc[0] += eel * f0; acc[1] += eel * f1;
    bf2(xa.y, f0, f1); acc[2] += eel * f0; acc[3] += eel * f1;
    bf2(xa.z, f0, f1); acc[4] += eel * f0; acc[5] += eel * f1;
    bf2(xa.w, f0, f1); acc[6] += eel * f0; acc[7] += eel * f1;
    bf2(xb.x, f0, f1); acc[8] += eel * f0; acc[9] += eel * f1;
    bf2(xb.y, f0, f1); acc[10] += eel * f0; acc[11] += eel * f1;
    bf2(xb.z, f0, f1); acc[12] += eel * f0; acc[13] += eel * f1;
    bf2(xb.w, f0, f1); acc[14] += eel * f0; acc[15] += eel * f1;
  }
  float inv = 1.f / (denom + 1e-16f);
  // 16x64 GEMV + relu/bias/lin_w epilogue: lane i handles h = i+16*step
  float o = 0.f;
#pragma unroll
  for (int stp = 0; stp < 4; ++stp) {
    int h = i + stp * 16;
    float oh = 0.f;
#pragma unroll
    for (int j = 0; j < F_IN; ++j) oh += acc[j] * sW[j * HDIM + h];
    o += fmaxf(oh * inv + bias[h], 0.f) * lin_w[h];
  }
#pragma unroll
  for (int off = 8; off > 0; off >>= 1) o += __shfl_xor(o, off, 16);
  if (i == 0) s_node[node] = o;
}

// ---- K5: out[e] = sigmoid(0.5*(s[src]+s[dst]) + lin_b) ----
__global__ __launch_bounds__(256) void k_out(
    const int* __restrict__ ei, const float* __restrict__ s_node,
    const float* __restrict__ lin_b, float* __restrict__ out) {
  int e = blockIdx.x * 256 + threadIdx.x;
  if (e >= N_EDGES) return;
  int s = __builtin_nontemporal_load(ei + e);
  int d = __builtin_nontemporal_load(ei + N_EDGES + e);
  float z = 0.5f * (s_node[s] + s_node[d]) + lin_b[0];
  float r = 1.f / (1.f + expf(-z));
  __builtin_nontemporal_store(r, out + e);
}

extern "C" void kernel_launch(void* const* d_in, const int* in_sizes, int n_in,
                              void* d_out, int out_size, void* d_ws, size_t ws_size,
                              hipStream_t stream) {
  const float* x        = (const float*)d_in[0];
  const float* edge_attr= (const float*)d_in[1];
  const float* W        = (const float*)d_in[2];
  const float* W_edge   = (const float*)d_in[3];
  const float* att_src  = (const float*)d_in[4];
  const float* att_dst  = (const float*)d_in[5];
  const float* att_edge = (const float*)d_in[6];
  const float* bias     = (const float*)d_in[7];
  const float* lin_w    = (const float*)d_in[8];
  const float* lin_b    = (const float*)d_in[9];
  const int*   ei       = (const int*)d_in[10];
  float* out = (float*)d_out;

  // workspace layout (16-B alignment for xbf/sstream preserved)
  char* base = (char*)d_ws;
  __hip_bfloat16* xbf = (__hip_bfloat16*)base;                      // N*16*2 = 3.2 MB
  ull* sstream = (ull*)(base + (size_t)N_NODES * F_IN * 2);         // 8*210000*8 = 13.44 MB
  unsigned* bpack = (unsigned*)(sstream + (size_t)NSLICE * SLICE_CAP); // N*CAP*4 = 25.6 MB
  ull* packed = (ull*)(bpack + (size_t)N_NODES * CAP);              // N*8 = 0.8 MB (zeroed)
  unsigned* gcount = (unsigned*)(packed + N_NODES);                 // 8*64 u32 (zeroed)
  float* a_src  = (float*)(gcount + NSLICE * GPAD);                 // N
  float* a_dst  = a_src + N_NODES;                                  // N
  float* s_node = a_dst + N_NODES;                                  // N
  float* w_e    = s_node + N_NODES;                                 // 16
  // total ~ 44.3 MB

  hipMemsetAsync(packed, 0,
                 sizeof(ull) * N_NODES + sizeof(unsigned) * NSLICE * GPAD, stream);

  int nb_node   = (N_NODES + 3) / 4;
  int nb_edge_t = N_EDGES / 256;    // 6250, exact
  int nb_gather = (N_NODES + 15) / 16;

  k_node_h  <<<nb_node, 256, 0, stream>>>(x, W, att_src, att_dst, xbf, a_src, a_dst);
  k_we      <<<1, 64, 0, stream>>>(W_edge, att_edge, w_e);
  k_edge_pre<<<nb_edge_t, 256, 0, stream>>>(edge_attr, ei, w_e, sstream, gcount);
  k_part2   <<<PART_BLOCKS, 256, 0, stream>>>(sstream, gcount, a_src, a_dst,
                                              packed, bpack);
  k_gather  <<<nb_gather, 256, 0, stream>>>(packed, bpack, xbf, W, a_src, a_dst,
                                            bias, lin_w, s_node);
  k_out     <<<nb_edge_t, 256, 0, stream>>>(ei, s_node, lin_b, out);
}

// Round 3
// 356.301 us; speedup vs baseline: 1.0213x; 1.0069x over previous
//
#include <hip/hip_runtime.h>
#include <hip/hip_bf16.h>
#include <hip/hip_fp16.h>
#include <math.h>

#define N_NODES 100000
#define N_EDGES 1600000
#define F_IN 16
#define HDIM 64
#define E_DIM 9
#define NEG 0.2f

#define NSLICE 8
#define SLICE_W 12500                     // dst-slice width (100000/8)
#define NSTRIPE 32                        // R2: tail-counter striping (same-addr atomic queue 6250->195)
#define STRIPE_CAP 7680                   // per-(slice,stripe) region; mean 6272 + 19 sigma
#define NSUB 64                           // sub-bins per slice
#define SUBW 196                          // nodes per sub-bin (64*196 = 12544 >= 12500)
#define SUB_CAP 4096                      // per-sub-bin entries; mean 3281 + 14 sigma
#define K3_CHUNK 1920                     // STRIPE_CAP/4
#define FIXSCALE 16777216.0f              // 2^24 fixed-point for sum_ae

typedef unsigned long long ull;
typedef long long ll;

__device__ __forceinline__ void bf2(unsigned u, float& lo, float& hi) {
  lo = __uint_as_float(u << 16);
  hi = __uint_as_float(u & 0xFFFF0000u);
}

// ---- K1: a_src/a_dst = (x@W)@att (wave per node); store x as bf16 row (32 B) ----
__global__ __launch_bounds__(256) void k_node_h(
    const float* __restrict__ x, const float* __restrict__ W,
    const float* __restrict__ att_src, const float* __restrict__ att_dst,
    __hip_bfloat16* __restrict__ xbf, float* __restrict__ a_src,
    float* __restrict__ a_dst) {
  __shared__ float sW[F_IN * HDIM];
  int t = threadIdx.x;
  for (int i = t; i < F_IN * HDIM; i += 256) sW[i] = W[i];
  __syncthreads();
  int lane = t & 63;
  int node = blockIdx.x * 4 + (t >> 6);
  if (node >= N_NODES) return;
  const float* xr = x + node * F_IN;
  float acc = 0.f;
#pragma unroll
  for (int k = 0; k < F_IN; ++k) acc += xr[k] * sW[k * HDIM + lane];
  if (lane < F_IN) xbf[(size_t)node * F_IN + lane] = __float2bfloat16(xr[lane]);
  float v1 = acc * att_src[lane];
  float v2 = acc * att_dst[lane];
#pragma unroll
  for (int off = 32; off > 0; off >>= 1) {
    v1 += __shfl_down(v1, off);
    v2 += __shfl_down(v2, off);
  }
  if (lane == 0) { a_src[node] = v1; a_dst[node] = v2; }
}

// ---- tiny: w_e[d] = sum_h W_edge[d,h]*att_edge[h] ----
__global__ void k_we(const float* __restrict__ W_edge,
                     const float* __restrict__ att_edge, float* __restrict__ w_e) {
  int d = threadIdx.x;
  if (d < E_DIM) {
    float s = 0.f;
    for (int hh = 0; hh < HDIM; ++hh) s += W_edge[d * HDIM + hh] * att_edge[hh];
    w_e[d] = s;
  }
}

// ---- K2: a_e dot + 8-way dst-slice partition (ballot compaction), R2: tail
// counters striped x32 so same-address atomic queue is ~195 deep, not 6250.
// Entry = {dloc:16 | fp16(a_e):16 | src:32}. ----
__global__ __launch_bounds__(256) void k_edge_pre(
    const float* __restrict__ ea, const int* __restrict__ ei,
    const float* __restrict__ w_e, ull* __restrict__ sstream,
    unsigned* __restrict__ gcount) {
  __shared__ float sea[256 * E_DIM];
  __shared__ float swe[E_DIM];
  __shared__ unsigned wcnt[4][NSLICE];
  __shared__ unsigned woff[4][NSLICE];
  __shared__ unsigned gbase[NSLICE];
  int t = threadIdx.x;
  int wave = t >> 6, lane = t & 63;
  unsigned stripe = blockIdx.x & (NSTRIPE - 1);
  if (t < E_DIM) swe[t] = w_e[t];
  size_t tile = (size_t)blockIdx.x * (256 * E_DIM);
#pragma unroll
  for (int i = 0; i < E_DIM; ++i)
    sea[i * 256 + t] = __builtin_nontemporal_load(ea + tile + i * 256 + t);
  int e = blockIdx.x * 256 + t;
  int s = __builtin_nontemporal_load(ei + e);
  int d = __builtin_nontemporal_load(ei + N_EDGES + e);
  __syncthreads();
  float a_e = 0.f;
#pragma unroll
  for (int k = 0; k < E_DIM; ++k) a_e += sea[t * E_DIM + k] * swe[k];
  unsigned slice = (unsigned)d / SLICE_W;
  unsigned dloc = (unsigned)d - slice * SLICE_W;
  unsigned aeh = (unsigned)__half_as_ushort(__float2half(a_e));
  ull entry = ((ull)dloc << 48) | ((ull)aeh << 32) | (ull)(unsigned)s;
  // wave-level ranking via ballot
  ull lt = (lane == 63) ? 0x7FFFFFFFFFFFFFFFull : ((1ull << lane) - 1ull);
  unsigned myrank = 0;
#pragma unroll
  for (int si = 0; si < NSLICE; ++si) {
    ull m = __ballot(slice == (unsigned)si);
    if (slice == (unsigned)si) myrank = (unsigned)__popcll(m & lt);
    if (lane == 0) wcnt[wave][si] = (unsigned)__popcll(m);
  }
  __syncthreads();
  if (t < NSLICE) {
    unsigned a = 0;
#pragma unroll
    for (int w = 0; w < 4; ++w) { woff[w][t] = a; a += wcnt[w][t]; }
    gbase[t] = atomicAdd(gcount + ((unsigned)t * NSTRIPE + stripe) * 16, a);
  }
  __syncthreads();
  unsigned off = gbase[slice] + woff[wave][slice] + myrank;
  if (off < STRIPE_CAP)
    __builtin_nontemporal_store(
        entry, sstream + (size_t)(slice * NSTRIPE + stripe) * STRIPE_CAP + off);
}

// ---- K3 (k_sub): re-partition striped slice streams into 64 sub-bins/slice
// (196 nodes each) via LDS histogram (global atomics: ~64/block, ~65K total
// vs 1.68M before). Folds the full logit math: gathers a_src/a_dst, computes
// ee = exp(leaky(al)). Out entry = {dlocs:8 | ee:bf16 | ae:f16 | 0:7 | src:17}. ----
__global__ __launch_bounds__(256) void k_sub(
    const ull* __restrict__ sstream, const unsigned* __restrict__ gcount,
    const float* __restrict__ a_src, const float* __restrict__ a_dst,
    ull* __restrict__ sub_stream, unsigned* __restrict__ sub_tail) {
  __shared__ unsigned hist[NSUB];
  __shared__ unsigned gb[NSUB];
  int t = threadIdx.x;
  int b = blockIdx.x;
  int slice = b & 7;
  int stripe = (b >> 3) & (NSTRIPE - 1);
  int chunk = b >> 8;                       // 0..3
  unsigned n = gcount[(slice * NSTRIPE + stripe) * 16];
  if (n > STRIPE_CAP) n = STRIPE_CAP;
  const ull* rb = sstream + (size_t)(slice * NSTRIPE + stripe) * STRIPE_CAP;
  unsigned start = (unsigned)chunk * K3_CHUNK;
  unsigned end = n < start + K3_CHUNK ? n : start + K3_CHUNK;
  if (t < NSUB) hist[t] = 0;
  __syncthreads();
  ull ent[8];
  unsigned bn[8];
  bool val[8];
#pragma unroll
  for (int u = 0; u < 8; ++u) {
    unsigned i = start + (unsigned)u * 256 + (unsigned)t;
    val[u] = (i < end);
    ent[u] = val[u] ? rb[i] : 0ull;
  }
#pragma unroll
  for (int u = 0; u < 8; ++u) {
    unsigned dloc = (unsigned)(ent[u] >> 48);
    bn[u] = dloc / SUBW;
    if (val[u]) atomicAdd(&hist[bn[u]], 1u);
  }
  // prefetch gathers while histogram settles
  float asv[8], adv[8];
#pragma unroll
  for (int u = 0; u < 8; ++u) {
    unsigned src = (unsigned)(ent[u] & 0xFFFFFFFFu);
    unsigned dloc = (unsigned)(ent[u] >> 48);
    asv[u] = val[u] ? a_src[src] : 0.f;
    adv[u] = val[u] ? a_dst[slice * SLICE_W + dloc] : 0.f;
  }
  __syncthreads();
  if (t < NSUB && hist[t]) gb[t] = atomicAdd(sub_tail + ((slice * NSUB + t) * 16), hist[t]);
  __syncthreads();
  if (t < NSUB) hist[t] = 0;                // reuse as per-bin cursor
  __syncthreads();
#pragma unroll
  for (int u = 0; u < 8; ++u) {
    if (!val[u]) continue;
    unsigned src = (unsigned)(ent[u] & 0xFFFFFFFFu);
    float ae = __half2float(__ushort_as_half((unsigned short)((ent[u] >> 32) & 0xFFFFu)));
    unsigned dloc = (unsigned)(ent[u] >> 48);
    float al = asv[u] + adv[u] + ae;
    al = al >= 0.f ? al : NEG * al;
    float ee = expf(al);                    // shift-invariant softmax
    unsigned bq = __float_as_uint(ee);
    bq += 0x7fffu + ((bq >> 16) & 1u);      // RNE to bf16
    unsigned ee16 = (bq >> 16) & 0xFFFFu;
    unsigned aeh = (unsigned)((ent[u] >> 32) & 0xFFFFu);
    unsigned dlocs = dloc - bn[u] * SUBW;   // 0..195
    ull e2 = ((ull)dlocs << 56) | ((ull)ee16 << 40) | ((ull)aeh << 24) | (ull)src;
    unsigned r = atomicAdd(&hist[bn[u]], 1u);
    unsigned pos = gb[bn[u]] + r;
    if (pos < SUB_CAP)
      sub_stream[(size_t)(slice * NSUB + bn[u]) * SUB_CAP + pos] = e2;
  }
}

// ---- K4 (k_acc): one WG owns one sub-bin (<=196 nodes) EXCLUSIVELY. Streams
// its entries coalesced; accumulates Sum ee*x[src] (16), denom, {cnt|sum_ae}
// in LDS (ds_add_f32/u64 — no global atomics). Then self-loop + 16x64 GEMV
// epilogue with fused relu/bias/lin_w. Replaces k_part2's 1.68M fabric
// atomics + k_gather's bpack round-trip. ----
__global__ __launch_bounds__(512) void k_acc(
    const ull* __restrict__ sub_stream, const unsigned* __restrict__ sub_tail,
    const __hip_bfloat16* __restrict__ xbf, const float* __restrict__ W,
    const float* __restrict__ a_src, const float* __restrict__ a_dst,
    const float* __restrict__ bias, const float* __restrict__ lin_w,
    float* __restrict__ s_node) {
  __shared__ float acc[SUBW * 17];          // 16 feature sums + denom, stride 17
  __shared__ ull cae[SUBW];                 // {sum_ae fixpt : 44 | cnt : 20}
  __shared__ float sW[F_IN * HDIM];
  __shared__ float sb[HDIM], sl[HDIM];
  int t = threadIdx.x;
  int slice = blockIdx.x & 7;
  int bin = blockIdx.x >> 3;
  int nbase = slice * SLICE_W + bin * SUBW;
  int nnodes = SLICE_W - bin * SUBW; if (nnodes > SUBW) nnodes = SUBW;   // 196 or 152
  for (int i = t; i < SUBW * 17; i += 512) acc[i] = 0.f;
  for (int i = t; i < SUBW; i += 512) cae[i] = 0ull;
  for (int i = t; i < F_IN * HDIM; i += 512) sW[i] = W[i];
  if (t < HDIM) { sb[t] = bias[t]; sl[t] = lin_w[t]; }
  __syncthreads();
  unsigned n = sub_tail[(slice * NSUB + bin) * 16];
  if (n > SUB_CAP) n = SUB_CAP;
  const ull* sp = sub_stream + (size_t)(slice * NSUB + bin) * SUB_CAP;
  for (unsigned i = (unsigned)t; i < n; i += 512) {
    ull e2 = sp[i];
    unsigned src = (unsigned)(e2 & 0x1FFFFu);
    float ae = __half2float(__ushort_as_half((unsigned short)((e2 >> 24) & 0xFFFFu)));
    float ee = __uint_as_float(((unsigned)((e2 >> 40) & 0xFFFFu)) << 16);
    unsigned dl = (unsigned)(e2 >> 56);
    const uint4* xp = (const uint4*)(xbf + (size_t)src * F_IN);
    uint4 xa = xp[0], xb = xp[1];
    float* ap = acc + dl * 17;
    float f0, f1;
    bf2(xa.x, f0, f1); atomicAdd(ap + 0, ee * f0);  atomicAdd(ap + 1, ee * f1);
    bf2(xa.y, f0, f1); atomicAdd(ap + 2, ee * f0);  atomicAdd(ap + 3, ee * f1);
    bf2(xa.z, f0, f1); atomicAdd(ap + 4, ee * f0);  atomicAdd(ap + 5, ee * f1);
    bf2(xa.w, f0, f1); atomicAdd(ap + 6, ee * f0);  atomicAdd(ap + 7, ee * f1);
    bf2(xb.x, f0, f1); atomicAdd(ap + 8, ee * f0);  atomicAdd(ap + 9, ee * f1);
    bf2(xb.y, f0, f1); atomicAdd(ap + 10, ee * f0); atomicAdd(ap + 11, ee * f1);
    bf2(xb.z, f0, f1); atomicAdd(ap + 12, ee * f0); atomicAdd(ap + 13, ee * f1);
    bf2(xb.w, f0, f1); atomicAdd(ap + 14, ee * f0); atomicAdd(ap + 15, ee * f1);
    atomicAdd(ap + 16, ee);
    ll q = (ll)lrintf(ae * FIXSCALE);
    atomicAdd(&cae[dl], ((ull)q << 20) | 1ull);
  }
  __syncthreads();
  int g = t >> 4, il = t & 15;              // 32 groups of 16 lanes
  for (int nl = g; nl < nnodes; nl += 32) {
    int node = nbase + nl;
    ull p = cae[nl];
    unsigned deg = (unsigned)(p & 0xFFFFFu);
    float sumae = (float)((double)((ll)p >> 20) * (1.0 / (double)FIXSCALE));
    float all = a_src[node] + a_dst[node] + sumae / fmaxf((float)deg, 1.f);
    all = all >= 0.f ? all : NEG * all;
    float eel = expf(all);
    const uint4* xp = (const uint4*)(xbf + (size_t)node * F_IN);
    uint4 xa = xp[0], xb = xp[1];
    float xv[F_IN];
    bf2(xa.x, xv[0], xv[1]);   bf2(xa.y, xv[2], xv[3]);
    bf2(xa.z, xv[4], xv[5]);   bf2(xa.w, xv[6], xv[7]);
    bf2(xb.x, xv[8], xv[9]);   bf2(xb.y, xv[10], xv[11]);
    bf2(xb.z, xv[12], xv[13]); bf2(xb.w, xv[14], xv[15]);
    float aj[F_IN];
#pragma unroll
    for (int j = 0; j < F_IN; ++j) aj[j] = acc[nl * 17 + j] + eel * xv[j];
    float denom = acc[nl * 17 + 16] + eel;
    float inv = 1.f / (denom + 1e-16f);
    float o = 0.f;
#pragma unroll
    for (int stp = 0; stp < 4; ++stp) {
      int h = il + stp * 16;
      float oh = 0.f;
#pragma unroll
      for (int j = 0; j < F_IN; ++j) oh += aj[j] * sW[j * HDIM + h];
      o += fmaxf(oh * inv + sb[h], 0.f) * sl[h];
    }
#pragma unroll
    for (int off = 8; off > 0; off >>= 1) o += __shfl_xor(o, off, 16);
    if (il == 0) s_node[node] = o;
  }
}

// ---- K5: out[e] = sigmoid(0.5*(s[src]+s[dst]) + lin_b) ----
__global__ __launch_bounds__(256) void k_out(
    const int* __restrict__ ei, const float* __restrict__ s_node,
    const float* __restrict__ lin_b, float* __restrict__ out) {
  int e = blockIdx.x * 256 + threadIdx.x;
  if (e >= N_EDGES) return;
  int s = __builtin_nontemporal_load(ei + e);
  int d = __builtin_nontemporal_load(ei + N_EDGES + e);
  float z = 0.5f * (s_node[s] + s_node[d]) + lin_b[0];
  float r = 1.f / (1.f + expf(-z));
  __builtin_nontemporal_store(r, out + e);
}

extern "C" void kernel_launch(void* const* d_in, const int* in_sizes, int n_in,
                              void* d_out, int out_size, void* d_ws, size_t ws_size,
                              hipStream_t stream) {
  const float* x        = (const float*)d_in[0];
  const float* edge_attr= (const float*)d_in[1];
  const float* W        = (const float*)d_in[2];
  const float* W_edge   = (const float*)d_in[3];
  const float* att_src  = (const float*)d_in[4];
  const float* att_dst  = (const float*)d_in[5];
  const float* att_edge = (const float*)d_in[6];
  const float* bias     = (const float*)d_in[7];
  const float* lin_w    = (const float*)d_in[8];
  const float* lin_b    = (const float*)d_in[9];
  const int*   ei       = (const int*)d_in[10];
  float* out = (float*)d_out;

  // workspace layout (16-B alignment preserved)
  char* base = (char*)d_ws;
  __hip_bfloat16* xbf = (__hip_bfloat16*)base;                      // 3.2 MB
  ull* sstream = (ull*)(base + (size_t)N_NODES * F_IN * 2);         // 256*7680*8 = 15.73 MB
  ull* sub_stream = sstream + (size_t)NSLICE * NSTRIPE * STRIPE_CAP; // 512*4096*8 = 16.78 MB
  unsigned* gcount = (unsigned*)(sub_stream + (size_t)NSLICE * NSUB * SUB_CAP); // 16 KB (zeroed)
  unsigned* sub_tail = gcount + NSLICE * NSTRIPE * 16;              // 32 KB (zeroed)
  float* a_src  = (float*)(sub_tail + NSLICE * NSUB * 16);          // N
  float* a_dst  = a_src + N_NODES;                                  // N
  float* s_node = a_dst + N_NODES;                                  // N
  float* w_e    = s_node + N_NODES;                                 // 16
  // total ~ 37 MB

  hipMemsetAsync(gcount, 0,
                 sizeof(unsigned) * (NSLICE * NSTRIPE * 16 + NSLICE * NSUB * 16),
                 stream);

  int nb_node   = (N_NODES + 3) / 4;
  int nb_edge_t = N_EDGES / 256;            // 6250, exact
  int nb_sub    = NSLICE * NSTRIPE * 4;     // 1024
  int nb_acc    = NSLICE * NSUB;            // 512

  k_node_h  <<<nb_node, 256, 0, stream>>>(x, W, att_src, att_dst, xbf, a_src, a_dst);
  k_we      <<<1, 64, 0, stream>>>(W_edge, att_edge, w_e);
  k_edge_pre<<<nb_edge_t, 256, 0, stream>>>(edge_attr, ei, w_e, sstream, gcount);
  k_sub     <<<nb_sub, 256, 0, stream>>>(sstream, gcount, a_src, a_dst,
                                         sub_stream, sub_tail);
  k_acc     <<<nb_acc, 512, 0, stream>>>(sub_stream, sub_tail, xbf, W,
                                         a_src, a_dst, bias, lin_w, s_node);
  k_out     <<<nb_edge_t, 256, 0, stream>>>(ei, s_node, lin_b, out);
}

// Round 4
// 243.395 us; speedup vs baseline: 1.4951x; 1.4639x over previous
//
#include <hip/hip_runtime.h>
#include <hip/hip_bf16.h>
#include <hip/hip_fp16.h>
#include <math.h>

#define N_NODES 100000
#define N_EDGES 1600000
#define F_IN 16
#define HDIM 64
#define E_DIM 9
#define NEG 0.2f

#define NSLICE 8
#define SLICE_W 12500                     // dst-slice width (100000/8)
#define NSTRIPE 32                        // tail-counter striping (R2)
#define STRIPE_CAP 7680                   // per-(slice,stripe) region
#define NSUB 128                          // R3: sub-bins per slice (was 64)
#define SUBW 98                           // nodes per sub-bin (128*98=12544>=12500)
#define SUB_CAP 2048                      // entries per sub-bin; mean 1568 + 12 sigma
#define K3_CHUNK 1920                     // STRIPE_CAP/4
#define FIXSCALE 16777216.0f

typedef unsigned long long ull;
typedef long long ll;

__device__ __forceinline__ void bf2(unsigned u, float& lo, float& hi) {
  lo = __uint_as_float(u << 16);
  hi = __uint_as_float(u & 0xFFFF0000u);
}

// ---- K1: a_src/a_dst = (x@W)@att (wave per node); store x as bf16 row (32 B) ----
__global__ __launch_bounds__(256) void k_node_h(
    const float* __restrict__ x, const float* __restrict__ W,
    const float* __restrict__ att_src, const float* __restrict__ att_dst,
    __hip_bfloat16* __restrict__ xbf, float* __restrict__ a_src,
    float* __restrict__ a_dst) {
  __shared__ float sW[F_IN * HDIM];
  int t = threadIdx.x;
  for (int i = t; i < F_IN * HDIM; i += 256) sW[i] = W[i];
  __syncthreads();
  int lane = t & 63;
  int node = blockIdx.x * 4 + (t >> 6);
  if (node >= N_NODES) return;
  const float* xr = x + node * F_IN;
  float acc = 0.f;
#pragma unroll
  for (int k = 0; k < F_IN; ++k) acc += xr[k] * sW[k * HDIM + lane];
  if (lane < F_IN) xbf[(size_t)node * F_IN + lane] = __float2bfloat16(xr[lane]);
  float v1 = acc * att_src[lane];
  float v2 = acc * att_dst[lane];
#pragma unroll
  for (int off = 32; off > 0; off >>= 1) {
    v1 += __shfl_down(v1, off);
    v2 += __shfl_down(v2, off);
  }
  if (lane == 0) { a_src[node] = v1; a_dst[node] = v2; }
}

// ---- tiny: w_e[d] = sum_h W_edge[d,h]*att_edge[h] ----
__global__ void k_we(const float* __restrict__ W_edge,
                     const float* __restrict__ att_edge, float* __restrict__ w_e) {
  int d = threadIdx.x;
  if (d < E_DIM) {
    float s = 0.f;
    for (int hh = 0; hh < HDIM; ++hh) s += W_edge[d * HDIM + hh] * att_edge[hh];
    w_e[d] = s;
  }
}

// ---- K2: a_e dot + 8-way dst-slice partition (ballot compaction), striped
// tail counters. Entry = {dloc:16 | fp16(a_e):16 | src:32}. ----
__global__ __launch_bounds__(256) void k_edge_pre(
    const float* __restrict__ ea, const int* __restrict__ ei,
    const float* __restrict__ w_e, ull* __restrict__ sstream,
    unsigned* __restrict__ gcount) {
  __shared__ float sea[256 * E_DIM];
  __shared__ float swe[E_DIM];
  __shared__ unsigned wcnt[4][NSLICE];
  __shared__ unsigned woff[4][NSLICE];
  __shared__ unsigned gbase[NSLICE];
  int t = threadIdx.x;
  int wave = t >> 6, lane = t & 63;
  unsigned stripe = blockIdx.x & (NSTRIPE - 1);
  if (t < E_DIM) swe[t] = w_e[t];
  size_t tile = (size_t)blockIdx.x * (256 * E_DIM);
#pragma unroll
  for (int i = 0; i < E_DIM; ++i)
    sea[i * 256 + t] = __builtin_nontemporal_load(ea + tile + i * 256 + t);
  int e = blockIdx.x * 256 + t;
  int s = __builtin_nontemporal_load(ei + e);
  int d = __builtin_nontemporal_load(ei + N_EDGES + e);
  __syncthreads();
  float a_e = 0.f;
#pragma unroll
  for (int k = 0; k < E_DIM; ++k) a_e += sea[t * E_DIM + k] * swe[k];
  unsigned slice = (unsigned)d / SLICE_W;
  unsigned dloc = (unsigned)d - slice * SLICE_W;
  unsigned aeh = (unsigned)__half_as_ushort(__float2half(a_e));
  ull entry = ((ull)dloc << 48) | ((ull)aeh << 32) | (ull)(unsigned)s;
  // wave-level ranking via ballot
  ull lt = (lane == 63) ? 0x7FFFFFFFFFFFFFFFull : ((1ull << lane) - 1ull);
  unsigned myrank = 0;
#pragma unroll
  for (int si = 0; si < NSLICE; ++si) {
    ull m = __ballot(slice == (unsigned)si);
    if (slice == (unsigned)si) myrank = (unsigned)__popcll(m & lt);
    if (lane == 0) wcnt[wave][si] = (unsigned)__popcll(m);
  }
  __syncthreads();
  if (t < NSLICE) {
    unsigned a = 0;
#pragma unroll
    for (int w = 0; w < 4; ++w) { woff[w][t] = a; a += wcnt[w][t]; }
    gbase[t] = atomicAdd(gcount + ((unsigned)t * NSTRIPE + stripe) * 16, a);
  }
  __syncthreads();
  unsigned off = gbase[slice] + woff[wave][slice] + myrank;
  if (off < STRIPE_CAP)
    __builtin_nontemporal_store(
        entry, sstream + (size_t)(slice * NSTRIPE + stripe) * STRIPE_CAP + off);
}

// ---- K3 (k_sub): re-partition striped slice streams into 128 sub-bins/slice
// (98 nodes each) via LDS histogram. Folds the logit math: gathers
// a_src/a_dst, ee = exp(leaky(al)). Out entry = {dlocs:8 | ee:bf16 | ae:f16 |
// src:24(17 used)}. ----
__global__ __launch_bounds__(256) void k_sub(
    const ull* __restrict__ sstream, const unsigned* __restrict__ gcount,
    const float* __restrict__ a_src, const float* __restrict__ a_dst,
    ull* __restrict__ sub_stream, unsigned* __restrict__ sub_tail) {
  __shared__ unsigned hist[NSUB];
  __shared__ unsigned gb[NSUB];
  int t = threadIdx.x;
  int b = blockIdx.x;
  int slice = b & 7;
  int stripe = (b >> 3) & (NSTRIPE - 1);
  int chunk = b >> 8;                       // 0..3
  unsigned n = gcount[(slice * NSTRIPE + stripe) * 16];
  if (n > STRIPE_CAP) n = STRIPE_CAP;
  const ull* rb = sstream + (size_t)(slice * NSTRIPE + stripe) * STRIPE_CAP;
  unsigned start = (unsigned)chunk * K3_CHUNK;
  unsigned end = n < start + K3_CHUNK ? n : start + K3_CHUNK;
  if (t < NSUB) hist[t] = 0;
  __syncthreads();
  ull ent[8];
  unsigned bn[8];
  bool val[8];
#pragma unroll
  for (int u = 0; u < 8; ++u) {
    unsigned i = start + (unsigned)u * 256 + (unsigned)t;
    val[u] = (i < end);
    ent[u] = val[u] ? rb[i] : 0ull;
  }
#pragma unroll
  for (int u = 0; u < 8; ++u) {
    unsigned dloc = (unsigned)(ent[u] >> 48);
    bn[u] = dloc / SUBW;
    if (val[u]) atomicAdd(&hist[bn[u]], 1u);
  }
  // prefetch gathers while histogram settles
  float asv[8], adv[8];
#pragma unroll
  for (int u = 0; u < 8; ++u) {
    unsigned src = (unsigned)(ent[u] & 0xFFFFFFFFu);
    unsigned dloc = (unsigned)(ent[u] >> 48);
    asv[u] = val[u] ? a_src[src] : 0.f;
    adv[u] = val[u] ? a_dst[slice * SLICE_W + dloc] : 0.f;
  }
  __syncthreads();
  if (t < NSUB && hist[t]) gb[t] = atomicAdd(sub_tail + ((slice * NSUB + t) * 16), hist[t]);
  __syncthreads();
  if (t < NSUB) hist[t] = 0;                // reuse as per-bin cursor
  __syncthreads();
#pragma unroll
  for (int u = 0; u < 8; ++u) {
    if (!val[u]) continue;
    unsigned src = (unsigned)(ent[u] & 0xFFFFFFFFu);
    float ae = __half2float(__ushort_as_half((unsigned short)((ent[u] >> 32) & 0xFFFFu)));
    unsigned dloc = (unsigned)(ent[u] >> 48);
    float al = asv[u] + adv[u] + ae;
    al = al >= 0.f ? al : NEG * al;
    float ee = expf(al);                    // shift-invariant softmax
    unsigned bq = __float_as_uint(ee);
    bq += 0x7fffu + ((bq >> 16) & 1u);      // RNE to bf16
    unsigned ee16 = (bq >> 16) & 0xFFFFu;
    unsigned aeh = (unsigned)((ent[u] >> 32) & 0xFFFFu);
    unsigned dlocs = dloc - bn[u] * SUBW;   // 0..97
    ull e2 = ((ull)dlocs << 56) | ((ull)ee16 << 40) | ((ull)aeh << 24) | (ull)src;
    unsigned r = atomicAdd(&hist[bn[u]], 1u);
    unsigned pos = gb[bn[u]] + r;
    if (pos < SUB_CAP)
      sub_stream[(size_t)(slice * NSUB + bn[u]) * SUB_CAP + pos] = e2;
  }
}

// ---- K4 (k_acc) R3: one WG owns one sub-bin (<=98 nodes). Phase A: in-LDS
// counting sort by local node id (1 LDS atomic/entry, shfl prefix over 128
// bins, 1 LDS scatter write) — replaces R2's 18 LDS atomics/entry. Phase B:
// 16 lanes/node stream the node's contiguous entries from LDS, gather
// xbf[src], accumulate acc[16]/denom/sum_ae in REGISTERS, shfl-reduce, fused
// 16x64 GEMV epilogue. ----
__global__ __launch_bounds__(512) void k_acc(
    const ull* __restrict__ sub_stream, const unsigned* __restrict__ sub_tail,
    const __hip_bfloat16* __restrict__ xbf, const float* __restrict__ W,
    const float* __restrict__ a_src, const float* __restrict__ a_dst,
    const float* __restrict__ bias, const float* __restrict__ lin_w,
    float* __restrict__ s_node) {
  __shared__ ull sorted[SUB_CAP];           // 16 KB
  __shared__ unsigned hist[NSUB];
  __shared__ unsigned pref[NSUB];
  __shared__ unsigned w0tot;
  __shared__ float sW[F_IN * HDIM];
  __shared__ float sb[HDIM], sl[HDIM];
  int t = threadIdx.x;
  int slice = blockIdx.x & 7;
  int bin = blockIdx.x >> 3;
  int nbase = slice * SLICE_W + bin * SUBW;
  int nnodes = SLICE_W - bin * SUBW; if (nnodes > SUBW) nnodes = SUBW;   // 98 or 54
  if (t < NSUB) hist[t] = 0;
  for (int i = t; i < F_IN * HDIM; i += 512) sW[i] = W[i];
  if (t < HDIM) { sb[t] = bias[t]; sl[t] = lin_w[t]; }
  __syncthreads();
  unsigned n = sub_tail[(slice * NSUB + bin) * 16];
  if (n > SUB_CAP) n = SUB_CAP;
  const ull* sp = sub_stream + (size_t)(slice * NSUB + bin) * SUB_CAP;
  // Phase A: count + rank
  ull ent[4];
  unsigned dl4[4], rk[4];
  bool val[4];
#pragma unroll
  for (int u = 0; u < 4; ++u) {
    unsigned i = (unsigned)u * 512 + (unsigned)t;
    val[u] = (i < n);
    ent[u] = val[u] ? sp[i] : 0ull;
  }
#pragma unroll
  for (int u = 0; u < 4; ++u) {
    dl4[u] = (unsigned)(ent[u] >> 56);
    if (val[u]) rk[u] = atomicAdd(&hist[dl4[u]], 1u);
  }
  __syncthreads();
  // exclusive prefix over 128 bins (waves 0,1 via shfl_up)
  if (t < NSUB) {
    unsigned v = hist[t];
    unsigned sc = v;
#pragma unroll
    for (int off = 1; off < 64; off <<= 1) {
      unsigned o = __shfl_up(sc, off);
      if ((t & 63) >= off) sc += o;
    }
    pref[t] = sc - v;                       // exclusive within wave
    if (t == 63) w0tot = sc;                // total of bins 0..63
  }
  __syncthreads();
  if (t >= 64 && t < NSUB) pref[t] += w0tot;
  __syncthreads();
  // scatter to sorted order
#pragma unroll
  for (int u = 0; u < 4; ++u)
    if (val[u]) sorted[pref[dl4[u]] + rk[u]] = ent[u];
  __syncthreads();
  // Phase B: per-node register accumulation (16 lanes/node, 32 groups)
  int g = t >> 4, il = t & 15;
  for (int nl = g; nl < nnodes; nl += 32) {
    int node = nbase + nl;
    unsigned start = pref[nl];
    unsigned cnt = hist[nl];
    float acc[F_IN];
#pragma unroll
    for (int j = 0; j < F_IN; ++j) acc[j] = 0.f;
    float denom = 0.f, sumae = 0.f;
    for (unsigned k = il; k < cnt; k += 16) {
      ull e2 = sorted[start + k];
      unsigned src = (unsigned)(e2 & 0xFFFFFFu);
      float ae = __half2float(__ushort_as_half((unsigned short)((e2 >> 24) & 0xFFFFu)));
      float ee = __uint_as_float(((unsigned)((e2 >> 40) & 0xFFFFu)) << 16);
      const uint4* xp = (const uint4*)(xbf + (size_t)src * F_IN);
      uint4 xa = xp[0], xb = xp[1];
      denom += ee;
      sumae += ae;
      float f0, f1;
      bf2(xa.x, f0, f1); acc[0] += ee * f0;  acc[1] += ee * f1;
      bf2(xa.y, f0, f1); acc[2] += ee * f0;  acc[3] += ee * f1;
      bf2(xa.z, f0, f1); acc[4] += ee * f0;  acc[5] += ee * f1;
      bf2(xa.w, f0, f1); acc[6] += ee * f0;  acc[7] += ee * f1;
      bf2(xb.x, f0, f1); acc[8] += ee * f0;  acc[9] += ee * f1;
      bf2(xb.y, f0, f1); acc[10] += ee * f0; acc[11] += ee * f1;
      bf2(xb.z, f0, f1); acc[12] += ee * f0; acc[13] += ee * f1;
      bf2(xb.w, f0, f1); acc[14] += ee * f0; acc[15] += ee * f1;
    }
#pragma unroll
    for (int off = 8; off > 0; off >>= 1) {
      denom += __shfl_xor(denom, off, 16);
      sumae += __shfl_xor(sumae, off, 16);
#pragma unroll
      for (int j = 0; j < F_IN; ++j) acc[j] += __shfl_xor(acc[j], off, 16);
    }
    // self-loop (fill_value='mean'): logit uses mean of incident a_e
    float all = a_src[node] + a_dst[node] + sumae / fmaxf((float)cnt, 1.f);
    all = all >= 0.f ? all : NEG * all;
    float eel = expf(all);
    denom += eel;
    {
      const uint4* xp = (const uint4*)(xbf + (size_t)node * F_IN);
      uint4 xa = xp[0], xb = xp[1];
      float f0, f1;
      bf2(xa.x, f0, f1); acc[0] += eel * f0;  acc[1] += eel * f1;
      bf2(xa.y, f0, f1); acc[2] += eel * f0;  acc[3] += eel * f1;
      bf2(xa.z, f0, f1); acc[4] += eel * f0;  acc[5] += eel * f1;
      bf2(xa.w, f0, f1); acc[6] += eel * f0;  acc[7] += eel * f1;
      bf2(xb.x, f0, f1); acc[8] += eel * f0;  acc[9] += eel * f1;
      bf2(xb.y, f0, f1); acc[10] += eel * f0; acc[11] += eel * f1;
      bf2(xb.z, f0, f1); acc[12] += eel * f0; acc[13] += eel * f1;
      bf2(xb.w, f0, f1); acc[14] += eel * f0; acc[15] += eel * f1;
    }
    float inv = 1.f / (denom + 1e-16f);
    float o = 0.f;
#pragma unroll
    for (int stp = 0; stp < 4; ++stp) {
      int h = il + stp * 16;
      float oh = 0.f;
#pragma unroll
      for (int j = 0; j < F_IN; ++j) oh += acc[j] * sW[j * HDIM + h];
      o += fmaxf(oh * inv + sb[h], 0.f) * sl[h];
    }
#pragma unroll
    for (int off = 8; off > 0; off >>= 1) o += __shfl_xor(o, off, 16);
    if (il == 0) s_node[node] = o;
  }
}

// ---- K5: out[e] = sigmoid(0.5*(s[src]+s[dst]) + lin_b) ----
__global__ __launch_bounds__(256) void k_out(
    const int* __restrict__ ei, const float* __restrict__ s_node,
    const float* __restrict__ lin_b, float* __restrict__ out) {
  int e = blockIdx.x * 256 + threadIdx.x;
  if (e >= N_EDGES) return;
  int s = __builtin_nontemporal_load(ei + e);
  int d = __builtin_nontemporal_load(ei + N_EDGES + e);
  float z = 0.5f * (s_node[s] + s_node[d]) + lin_b[0];
  float r = 1.f / (1.f + expf(-z));
  __builtin_nontemporal_store(r, out + e);
}

extern "C" void kernel_launch(void* const* d_in, const int* in_sizes, int n_in,
                              void* d_out, int out_size, void* d_ws, size_t ws_size,
                              hipStream_t stream) {
  const float* x        = (const float*)d_in[0];
  const float* edge_attr= (const float*)d_in[1];
  const float* W        = (const float*)d_in[2];
  const float* W_edge   = (const float*)d_in[3];
  const float* att_src  = (const float*)d_in[4];
  const float* att_dst  = (const float*)d_in[5];
  const float* att_edge = (const float*)d_in[6];
  const float* bias     = (const float*)d_in[7];
  const float* lin_w    = (const float*)d_in[8];
  const float* lin_b    = (const float*)d_in[9];
  const int*   ei       = (const int*)d_in[10];
  float* out = (float*)d_out;

  // workspace layout (16-B alignment preserved)
  char* base = (char*)d_ws;
  __hip_bfloat16* xbf = (__hip_bfloat16*)base;                      // 3.2 MB
  ull* sstream = (ull*)(base + (size_t)N_NODES * F_IN * 2);         // 256*7680*8 = 15.73 MB
  ull* sub_stream = sstream + (size_t)NSLICE * NSTRIPE * STRIPE_CAP; // 1024*2048*8 = 16.78 MB
  unsigned* gcount = (unsigned*)(sub_stream + (size_t)NSLICE * NSUB * SUB_CAP); // 16 KB (zeroed)
  unsigned* sub_tail = gcount + NSLICE * NSTRIPE * 16;              // 64 KB (zeroed)
  float* a_src  = (float*)(sub_tail + NSLICE * NSUB * 16);          // N
  float* a_dst  = a_src + N_NODES;                                  // N
  float* s_node = a_dst + N_NODES;                                  // N
  float* w_e    = s_node + N_NODES;                                 // 16
  // total ~ 37 MB

  hipMemsetAsync(gcount, 0,
                 sizeof(unsigned) * (NSLICE * NSTRIPE * 16 + NSLICE * NSUB * 16),
                 stream);

  int nb_node   = (N_NODES + 3) / 4;
  int nb_edge_t = N_EDGES / 256;            // 6250, exact
  int nb_sub    = NSLICE * NSTRIPE * 4;     // 1024
  int nb_acc    = NSLICE * NSUB;            // 1024

  k_node_h  <<<nb_node, 256, 0, stream>>>(x, W, att_src, att_dst, xbf, a_src, a_dst);
  k_we      <<<1, 64, 0, stream>>>(W_edge, att_edge, w_e);
  k_edge_pre<<<nb_edge_t, 256, 0, stream>>>(edge_attr, ei, w_e, sstream, gcount);
  k_sub     <<<nb_sub, 256, 0, stream>>>(sstream, gcount, a_src, a_dst,
                                         sub_stream, sub_tail);
  k_acc     <<<nb_acc, 512, 0, stream>>>(sub_stream, sub_tail, xbf, W,
                                         a_src, a_dst, bias, lin_w, s_node);
  k_out     <<<nb_edge_t, 256, 0, stream>>>(ei, s_node, lin_b, out);
}

// Round 5
// 210.843 us; speedup vs baseline: 1.7259x; 1.1544x over previous
//
#include <hip/hip_runtime.h>
#include <hip/hip_bf16.h>
#include <hip/hip_fp16.h>
#include <math.h>

#define N_NODES 100000
#define N_EDGES 1600000
#define F_IN 16
#define HDIM 64
#define E_DIM 9
#define NEG 0.2f

#define NSLICE 8
#define SLICE_W 12500                     // dst-slice width (100000/8)
#define NSTRIPE 32                        // tail-counter striping (R2)
#define STRIPE_CAP 7680                   // per-(slice,stripe) region
#define NSUB 128                          // sub-bins per slice
#define SUBW 98                           // nodes per sub-bin (128*98=12544>=12500)
#define SUB_CAP 2048                      // entries per sub-bin; mean 1568 + 12 sigma
#define K3_CHUNK 1920                     // STRIPE_CAP/4
#define FIXSCALE 16777216.0f

typedef unsigned long long ull;
typedef long long ll;

__device__ __forceinline__ void bf2(unsigned u, float& lo, float& hi) {
  lo = __uint_as_float(u << 16);
  hi = __uint_as_float(u & 0xFFFF0000u);
}

__device__ __forceinline__ unsigned bfpack(float a, float b) {
  unsigned ua = __float_as_uint(a); ua += 0x7fffu + ((ua >> 16) & 1u);
  unsigned ub = __float_as_uint(b); ub += 0x7fffu + ((ub >> 16) & 1u);
  return (ua >> 16) | (ub & 0xFFFF0000u);
}

// ---- K0 (k_we): tiny precompute. w_e[d] = sum_h W_edge[d,h]*att_edge[h];
// R4: also wa_src[k] = sum_h W[k,h]*att_src[h], wa_dst likewise — this lets
// k_node_h compute a_src = x@(W@att_src) per-THREAD (no wave GEMV, no LDS W).
// Layout: w_e[0..8], wa_src at +16, wa_dst at +32. ----
__global__ void k_we(const float* __restrict__ W_edge,
                     const float* __restrict__ att_edge,
                     const float* __restrict__ W,
                     const float* __restrict__ att_src,
                     const float* __restrict__ att_dst,
                     float* __restrict__ w_e) {
  int d = threadIdx.x;
  if (d < E_DIM) {
    float s = 0.f;
    for (int hh = 0; hh < HDIM; ++hh) s += W_edge[d * HDIM + hh] * att_edge[hh];
    w_e[d] = s;
  }
  if (d >= 16 && d < 32) {
    int k = d - 16;
    float s = 0.f;
    for (int hh = 0; hh < HDIM; ++hh) s += W[k * HDIM + hh] * att_src[hh];
    w_e[16 + k] = s;
  }
  if (d >= 32 && d < 48) {
    int k = d - 32;
    float s = 0.f;
    for (int hh = 0; hh < HDIM; ++hh) s += W[k * HDIM + hh] * att_dst[hh];
    w_e[32 + k] = s;
  }
}

// ---- K1 (k_node_h) R4: one THREAD per node (was one wave). 4x float4 load,
// 32 FMA vs LDS-resident wa[32], bf16-pack x row, 2x uint4 store. No W
// staging, no shuffles. 391 blocks. ----
__global__ __launch_bounds__(256) void k_node_h(
    const float* __restrict__ x, const float* __restrict__ w_e,
    __hip_bfloat16* __restrict__ xbf, float* __restrict__ a_src,
    float* __restrict__ a_dst) {
  __shared__ float swa[32];
  int t = threadIdx.x;
  if (t < 32) swa[t] = w_e[16 + t];
  __syncthreads();
  int node = blockIdx.x * 256 + t;
  if (node >= N_NODES) return;
  const float4* xp = (const float4*)(x + (size_t)node * F_IN);
  float4 v0 = xp[0], v1 = xp[1], v2 = xp[2], v3 = xp[3];
  float xv[F_IN] = {v0.x, v0.y, v0.z, v0.w, v1.x, v1.y, v1.z, v1.w,
                    v2.x, v2.y, v2.z, v2.w, v3.x, v3.y, v3.z, v3.w};
  float s1 = 0.f, s2 = 0.f;
#pragma unroll
  for (int k = 0; k < F_IN; ++k) {
    s1 += xv[k] * swa[k];
    s2 += xv[k] * swa[16 + k];
  }
  a_src[node] = s1;
  a_dst[node] = s2;
  uint4 p0, p1;
  p0.x = bfpack(xv[0], xv[1]);   p0.y = bfpack(xv[2], xv[3]);
  p0.z = bfpack(xv[4], xv[5]);   p0.w = bfpack(xv[6], xv[7]);
  p1.x = bfpack(xv[8], xv[9]);   p1.y = bfpack(xv[10], xv[11]);
  p1.z = bfpack(xv[12], xv[13]); p1.w = bfpack(xv[14], xv[15]);
  uint4* op = (uint4*)(xbf + (size_t)node * F_IN);
  op[0] = p0;
  op[1] = p1;
}

// ---- K2: a_e dot + 8-way dst-slice partition (ballot compaction), striped
// tail counters. Entry = {dloc:16 | fp16(a_e):16 | src:32}. ----
__global__ __launch_bounds__(256) void k_edge_pre(
    const float* __restrict__ ea, const int* __restrict__ ei,
    const float* __restrict__ w_e, ull* __restrict__ sstream,
    unsigned* __restrict__ gcount) {
  __shared__ float sea[256 * E_DIM];
  __shared__ float swe[E_DIM];
  __shared__ unsigned wcnt[4][NSLICE];
  __shared__ unsigned woff[4][NSLICE];
  __shared__ unsigned gbase[NSLICE];
  int t = threadIdx.x;
  int wave = t >> 6, lane = t & 63;
  unsigned stripe = blockIdx.x & (NSTRIPE - 1);
  if (t < E_DIM) swe[t] = w_e[t];
  size_t tile = (size_t)blockIdx.x * (256 * E_DIM);
#pragma unroll
  for (int i = 0; i < E_DIM; ++i)
    sea[i * 256 + t] = __builtin_nontemporal_load(ea + tile + i * 256 + t);
  int e = blockIdx.x * 256 + t;
  int s = __builtin_nontemporal_load(ei + e);
  int d = __builtin_nontemporal_load(ei + N_EDGES + e);
  __syncthreads();
  float a_e = 0.f;
#pragma unroll
  for (int k = 0; k < E_DIM; ++k) a_e += sea[t * E_DIM + k] * swe[k];
  unsigned slice = (unsigned)d / SLICE_W;
  unsigned dloc = (unsigned)d - slice * SLICE_W;
  unsigned aeh = (unsigned)__half_as_ushort(__float2half(a_e));
  ull entry = ((ull)dloc << 48) | ((ull)aeh << 32) | (ull)(unsigned)s;
  // wave-level ranking via ballot
  ull lt = (lane == 63) ? 0x7FFFFFFFFFFFFFFFull : ((1ull << lane) - 1ull);
  unsigned myrank = 0;
#pragma unroll
  for (int si = 0; si < NSLICE; ++si) {
    ull m = __ballot(slice == (unsigned)si);
    if (slice == (unsigned)si) myrank = (unsigned)__popcll(m & lt);
    if (lane == 0) wcnt[wave][si] = (unsigned)__popcll(m);
  }
  __syncthreads();
  if (t < NSLICE) {
    unsigned a = 0;
#pragma unroll
    for (int w = 0; w < 4; ++w) { woff[w][t] = a; a += wcnt[w][t]; }
    gbase[t] = atomicAdd(gcount + ((unsigned)t * NSTRIPE + stripe) * 16, a);
  }
  __syncthreads();
  unsigned off = gbase[slice] + woff[wave][slice] + myrank;
  if (off < STRIPE_CAP)
    __builtin_nontemporal_store(
        entry, sstream + (size_t)(slice * NSTRIPE + stripe) * STRIPE_CAP + off);
}

// ---- K3 (k_sub): re-partition striped slice streams into 128 sub-bins/slice
// (98 nodes each) via LDS histogram. Folds the logit math: gathers
// a_src/a_dst, ee = exp(leaky(al)). Out entry = {dlocs:8 | ee:bf16 | ae:f16 |
// src:24(17 used)}. ----
__global__ __launch_bounds__(256) void k_sub(
    const ull* __restrict__ sstream, const unsigned* __restrict__ gcount,
    const float* __restrict__ a_src, const float* __restrict__ a_dst,
    ull* __restrict__ sub_stream, unsigned* __restrict__ sub_tail) {
  __shared__ unsigned hist[NSUB];
  __shared__ unsigned gb[NSUB];
  int t = threadIdx.x;
  int b = blockIdx.x;
  int slice = b & 7;
  int stripe = (b >> 3) & (NSTRIPE - 1);
  int chunk = b >> 8;                       // 0..3
  unsigned n = gcount[(slice * NSTRIPE + stripe) * 16];
  if (n > STRIPE_CAP) n = STRIPE_CAP;
  const ull* rb = sstream + (size_t)(slice * NSTRIPE + stripe) * STRIPE_CAP;
  unsigned start = (unsigned)chunk * K3_CHUNK;
  unsigned end = n < start + K3_CHUNK ? n : start + K3_CHUNK;
  if (t < NSUB) hist[t] = 0;
  __syncthreads();
  ull ent[8];
  unsigned bn[8];
  bool val[8];
#pragma unroll
  for (int u = 0; u < 8; ++u) {
    unsigned i = start + (unsigned)u * 256 + (unsigned)t;
    val[u] = (i < end);
    ent[u] = val[u] ? rb[i] : 0ull;
  }
#pragma unroll
  for (int u = 0; u < 8; ++u) {
    unsigned dloc = (unsigned)(ent[u] >> 48);
    bn[u] = dloc / SUBW;
    if (val[u]) atomicAdd(&hist[bn[u]], 1u);
  }
  // prefetch gathers while histogram settles
  float asv[8], adv[8];
#pragma unroll
  for (int u = 0; u < 8; ++u) {
    unsigned src = (unsigned)(ent[u] & 0xFFFFFFFFu);
    unsigned dloc = (unsigned)(ent[u] >> 48);
    asv[u] = val[u] ? a_src[src] : 0.f;
    adv[u] = val[u] ? a_dst[slice * SLICE_W + dloc] : 0.f;
  }
  __syncthreads();
  if (t < NSUB && hist[t]) gb[t] = atomicAdd(sub_tail + ((slice * NSUB + t) * 16), hist[t]);
  __syncthreads();
  if (t < NSUB) hist[t] = 0;                // reuse as per-bin cursor
  __syncthreads();
#pragma unroll
  for (int u = 0; u < 8; ++u) {
    if (!val[u]) continue;
    unsigned src = (unsigned)(ent[u] & 0xFFFFFFFFu);
    float ae = __half2float(__ushort_as_half((unsigned short)((ent[u] >> 32) & 0xFFFFu)));
    unsigned dloc = (unsigned)(ent[u] >> 48);
    float al = asv[u] + adv[u] + ae;
    al = al >= 0.f ? al : NEG * al;
    float ee = expf(al);                    // shift-invariant softmax
    unsigned bq = __float_as_uint(ee);
    bq += 0x7fffu + ((bq >> 16) & 1u);      // RNE to bf16
    unsigned ee16 = (bq >> 16) & 0xFFFFu;
    unsigned aeh = (unsigned)((ent[u] >> 32) & 0xFFFFu);
    unsigned dlocs = dloc - bn[u] * SUBW;   // 0..97
    ull e2 = ((ull)dlocs << 56) | ((ull)ee16 << 40) | ((ull)aeh << 24) | (ull)src;
    unsigned r = atomicAdd(&hist[bn[u]], 1u);
    unsigned pos = gb[bn[u]] + r;
    if (pos < SUB_CAP)
      sub_stream[(size_t)(slice * NSUB + bn[u]) * SUB_CAP + pos] = e2;
  }
}

// ---- K4 (k_acc): one WG owns one sub-bin (<=98 nodes). Phase A: in-LDS
// counting sort by local node id (1 LDS atomic/entry, shfl prefix over 128
// bins, 1 LDS scatter write). Phase B: 16 lanes/node stream the node's
// contiguous entries from LDS, gather xbf[src], accumulate in REGISTERS,
// shfl-reduce, fused 16x64 GEMV epilogue. ----
__global__ __launch_bounds__(512) void k_acc(
    const ull* __restrict__ sub_stream, const unsigned* __restrict__ sub_tail,
    const __hip_bfloat16* __restrict__ xbf, const float* __restrict__ W,
    const float* __restrict__ a_src, const float* __restrict__ a_dst,
    const float* __restrict__ bias, const float* __restrict__ lin_w,
    float* __restrict__ s_node) {
  __shared__ ull sorted[SUB_CAP];           // 16 KB
  __shared__ unsigned hist[NSUB];
  __shared__ unsigned pref[NSUB];
  __shared__ unsigned w0tot;
  __shared__ float sW[F_IN * HDIM];
  __shared__ float sb[HDIM], sl[HDIM];
  int t = threadIdx.x;
  int slice = blockIdx.x & 7;
  int bin = blockIdx.x >> 3;
  int nbase = slice * SLICE_W + bin * SUBW;
  int nnodes = SLICE_W - bin * SUBW; if (nnodes > SUBW) nnodes = SUBW;   // 98 or 54
  if (t < NSUB) hist[t] = 0;
  for (int i = t; i < F_IN * HDIM; i += 512) sW[i] = W[i];
  if (t < HDIM) { sb[t] = bias[t]; sl[t] = lin_w[t]; }
  __syncthreads();
  unsigned n = sub_tail[(slice * NSUB + bin) * 16];
  if (n > SUB_CAP) n = SUB_CAP;
  const ull* sp = sub_stream + (size_t)(slice * NSUB + bin) * SUB_CAP;
  // Phase A: count + rank
  ull ent[4];
  unsigned dl4[4], rk[4];
  bool val[4];
#pragma unroll
  for (int u = 0; u < 4; ++u) {
    unsigned i = (unsigned)u * 512 + (unsigned)t;
    val[u] = (i < n);
    ent[u] = val[u] ? sp[i] : 0ull;
  }
#pragma unroll
  for (int u = 0; u < 4; ++u) {
    dl4[u] = (unsigned)(ent[u] >> 56);
    if (val[u]) rk[u] = atomicAdd(&hist[dl4[u]], 1u);
  }
  __syncthreads();
  // exclusive prefix over 128 bins (waves 0,1 via shfl_up)
  if (t < NSUB) {
    unsigned v = hist[t];
    unsigned sc = v;
#pragma unroll
    for (int off = 1; off < 64; off <<= 1) {
      unsigned o = __shfl_up(sc, off);
      if ((t & 63) >= off) sc += o;
    }
    pref[t] = sc - v;                       // exclusive within wave
    if (t == 63) w0tot = sc;                // total of bins 0..63
  }
  __syncthreads();
  if (t >= 64 && t < NSUB) pref[t] += w0tot;
  __syncthreads();
  // scatter to sorted order
#pragma unroll
  for (int u = 0; u < 4; ++u)
    if (val[u]) sorted[pref[dl4[u]] + rk[u]] = ent[u];
  __syncthreads();
  // Phase B: per-node register accumulation (16 lanes/node, 32 groups)
  int g = t >> 4, il = t & 15;
  for (int nl = g; nl < nnodes; nl += 32) {
    int node = nbase + nl;
    unsigned start = pref[nl];
    unsigned cnt = hist[nl];
    float acc[F_IN];
#pragma unroll
    for (int j = 0; j < F_IN; ++j) acc[j] = 0.f;
    float denom = 0.f, sumae = 0.f;
    for (unsigned k = il; k < cnt; k += 16) {
      ull e2 = sorted[start + k];
      unsigned src = (unsigned)(e2 & 0xFFFFFFu);
      float ae = __half2float(__ushort_as_half((unsigned short)((e2 >> 24) & 0xFFFFu)));
      float ee = __uint_as_float(((unsigned)((e2 >> 40) & 0xFFFFu)) << 16);
      const uint4* xp = (const uint4*)(xbf + (size_t)src * F_IN);
      uint4 xa = xp[0], xb = xp[1];
      denom += ee;
      sumae += ae;
      float f0, f1;
      bf2(xa.x, f0, f1); acc[0] += ee * f0;  acc[1] += ee * f1;
      bf2(xa.y, f0, f1); acc[2] += ee * f0;  acc[3] += ee * f1;
      bf2(xa.z, f0, f1); acc[4] += ee * f0;  acc[5] += ee * f1;
      bf2(xa.w, f0, f1); acc[6] += ee * f0;  acc[7] += ee * f1;
      bf2(xb.x, f0, f1); acc[8] += ee * f0;  acc[9] += ee * f1;
      bf2(xb.y, f0, f1); acc[10] += ee * f0; acc[11] += ee * f1;
      bf2(xb.z, f0, f1); acc[12] += ee * f0; acc[13] += ee * f1;
      bf2(xb.w, f0, f1); acc[14] += ee * f0; acc[15] += ee * f1;
    }
#pragma unroll
    for (int off = 8; off > 0; off >>= 1) {
      denom += __shfl_xor(denom, off, 16);
      sumae += __shfl_xor(sumae, off, 16);
#pragma unroll
      for (int j = 0; j < F_IN; ++j) acc[j] += __shfl_xor(acc[j], off, 16);
    }
    // self-loop (fill_value='mean'): logit uses mean of incident a_e
    float all = a_src[node] + a_dst[node] + sumae / fmaxf((float)cnt, 1.f);
    all = all >= 0.f ? all : NEG * all;
    float eel = expf(all);
    denom += eel;
    {
      const uint4* xp = (const uint4*)(xbf + (size_t)node * F_IN);
      uint4 xa = xp[0], xb = xp[1];
      float f0, f1;
      bf2(xa.x, f0, f1); acc[0] += eel * f0;  acc[1] += eel * f1;
      bf2(xa.y, f0, f1); acc[2] += eel * f0;  acc[3] += eel * f1;
      bf2(xa.z, f0, f1); acc[4] += eel * f0;  acc[5] += eel * f1;
      bf2(xa.w, f0, f1); acc[6] += eel * f0;  acc[7] += eel * f1;
      bf2(xb.x, f0, f1); acc[8] += eel * f0;  acc[9] += eel * f1;
      bf2(xb.y, f0, f1); acc[10] += eel * f0; acc[11] += eel * f1;
      bf2(xb.z, f0, f1); acc[12] += eel * f0; acc[13] += eel * f1;
      bf2(xb.w, f0, f1); acc[14] += eel * f0; acc[15] += eel * f1;
    }
    float inv = 1.f / (denom + 1e-16f);
    float o = 0.f;
#pragma unroll
    for (int stp = 0; stp < 4; ++stp) {
      int h = il + stp * 16;
      float oh = 0.f;
#pragma unroll
      for (int j = 0; j < F_IN; ++j) oh += acc[j] * sW[j * HDIM + h];
      o += fmaxf(oh * inv + sb[h], 0.f) * sl[h];
    }
#pragma unroll
    for (int off = 8; off > 0; off >>= 1) o += __shfl_xor(o, off, 16);
    if (il == 0) s_node[node] = o;
  }
}

// ---- K5: out[e] = sigmoid(0.5*(s[src]+s[dst]) + lin_b) ----
__global__ __launch_bounds__(256) void k_out(
    const int* __restrict__ ei, const float* __restrict__ s_node,
    const float* __restrict__ lin_b, float* __restrict__ out) {
  int e = blockIdx.x * 256 + threadIdx.x;
  if (e >= N_EDGES) return;
  int s = __builtin_nontemporal_load(ei + e);
  int d = __builtin_nontemporal_load(ei + N_EDGES + e);
  float z = 0.5f * (s_node[s] + s_node[d]) + lin_b[0];
  float r = 1.f / (1.f + expf(-z));
  __builtin_nontemporal_store(r, out + e);
}

extern "C" void kernel_launch(void* const* d_in, const int* in_sizes, int n_in,
                              void* d_out, int out_size, void* d_ws, size_t ws_size,
                              hipStream_t stream) {
  const float* x        = (const float*)d_in[0];
  const float* edge_attr= (const float*)d_in[1];
  const float* W        = (const float*)d_in[2];
  const float* W_edge   = (const float*)d_in[3];
  const float* att_src  = (const float*)d_in[4];
  const float* att_dst  = (const float*)d_in[5];
  const float* att_edge = (const float*)d_in[6];
  const float* bias     = (const float*)d_in[7];
  const float* lin_w    = (const float*)d_in[8];
  const float* lin_b    = (const float*)d_in[9];
  const int*   ei       = (const int*)d_in[10];
  float* out = (float*)d_out;

  // workspace layout (16-B alignment preserved)
  char* base = (char*)d_ws;
  __hip_bfloat16* xbf = (__hip_bfloat16*)base;                      // 3.2 MB
  ull* sstream = (ull*)(base + (size_t)N_NODES * F_IN * 2);         // 256*7680*8 = 15.73 MB
  ull* sub_stream = sstream + (size_t)NSLICE * NSTRIPE * STRIPE_CAP; // 1024*2048*8 = 16.78 MB
  unsigned* gcount = (unsigned*)(sub_stream + (size_t)NSLICE * NSUB * SUB_CAP); // 16 KB (zeroed)
  unsigned* sub_tail = gcount + NSLICE * NSTRIPE * 16;              // 64 KB (zeroed)
  float* a_src  = (float*)(sub_tail + NSLICE * NSUB * 16);          // N
  float* a_dst  = a_src + N_NODES;                                  // N
  float* s_node = a_dst + N_NODES;                                  // N
  float* w_e    = s_node + N_NODES;                                 // 48 floats
  // total ~ 37 MB

  hipMemsetAsync(gcount, 0,
                 sizeof(unsigned) * (NSLICE * NSTRIPE * 16 + NSLICE * NSUB * 16),
                 stream);

  int nb_node   = (N_NODES + 255) / 256;    // 391
  int nb_edge_t = N_EDGES / 256;            // 6250, exact
  int nb_sub    = NSLICE * NSTRIPE * 4;     // 1024
  int nb_acc    = NSLICE * NSUB;            // 1024

  k_we      <<<1, 64, 0, stream>>>(W_edge, att_edge, W, att_src, att_dst, w_e);
  k_node_h  <<<nb_node, 256, 0, stream>>>(x, w_e, xbf, a_src, a_dst);
  k_edge_pre<<<nb_edge_t, 256, 0, stream>>>(edge_attr, ei, w_e, sstream, gcount);
  k_sub     <<<nb_sub, 256, 0, stream>>>(sstream, gcount, a_src, a_dst,
                                         sub_stream, sub_tail);
  k_acc     <<<nb_acc, 512, 0, stream>>>(sub_stream, sub_tail, xbf, W,
                                         a_src, a_dst, bias, lin_w, s_node);
  k_out     <<<nb_edge_t, 256, 0, stream>>>(ei, s_node, lin_b, out);
}